// Round 16
// baseline (55.220 us; speedup 1.0000x reference)
//
#include <hip/hip_runtime.h>
#include <math.h>

// PolyaTree R16: FP-bits bucket -> ancestor node -> short exact descent.
// Boundaries cluster exponentially near 0 and 1; float bits of min(x,1-x)
// give log-matched buckets on BOTH tails (R6's uniform grid failed exactly
// here). Bucket stores deepest tree node containing the whole bucket (u8);
// eval continues the R3-proven descent from there (identical compares ->
// bit-exact, absmax 0.03125 across R3..R15). Chain depth 8 -> ~3,
// DS instrs/pd 8 -> ~3.5. Leaf values gathered from global L1 (batched).

constexpr int DIMS  = 16;
constexpr int NODES = 255;
constexpr int XBASE = 7272;       // bits(1e-4f)>>17  (0x38D1B717>>17)
constexpr int SIDE  = 793;        // (bits(0.5f)>>17 = 8064) - XBASE + 1
constexpr int NBUK  = 2 * SIDE;   // 1586 buckets per dim
constexpr int BSTR  = 1600;       // padded per-dim bucket stride (bytes)

// --- exact-mirror node interval descent (validated R3..R15) ---
__device__ void node_lohi(const float* s, int j, float& lo, float& hi, float& acc) {
#pragma clang fp contract(off)
    unsigned key = (unsigned)(j + 1);
    int level = 31 - __clz(key);
    lo = 0.0f; hi = 1.0f; acc = 0.0f;
    int i = 0;
    for (int tb = level - 1; tb >= 0; --tb) {
        float b = s[i];
        acc += logf(b);
        float len = hi - lo;
        float split = lo + b * len;       // EXACT mirror of reference (no fma)
        unsigned bit = (key >> tb) & 1u;
        if (bit == 0u) { hi = split; }
        else { lo = split; hi = split + (1.0f - b) * len; }
        i = 2 * i + 1 + (int)bit;
    }
}

// one block per dim: phase A = splits+values (proven exact), phase B = buckets
__global__ __launch_bounds__(256) void build_tables(
    const float* __restrict__ samples,      // (16,255)
    float* __restrict__ ws_split,           // 16*128 f32
    float* __restrict__ ws_value,           // 16*128 f32
    unsigned char* __restrict__ ws_bucket)  // 16*BSTR u8
{
#pragma clang fp contract(off)
    const int d = blockIdx.x, tid = threadIdx.x;
    const float* s = samples + d * NODES;
    __shared__ float l_split[127];

    if (tid < NODES) {
        float lo, hi, acc;
        node_lohi(s, tid, lo, hi, acc);
        float b = s[tid];
        if (tid < 127) {
            float sp = lo + b * (hi - lo);          // exact mirror
            l_split[tid] = sp;
            ws_split[d * 128 + tid] = sp;
        } else {
            ws_value[d * 128 + (tid - 127)] = acc + logf(b) - logf(hi - lo);
        }
    }
    __syncthreads();

    for (int c = tid; c < NBUK; c += 256) {
        float xmin, xmax;
        if (c < SIDE) {                              // x-side: key = x itself
            unsigned blo = (unsigned)(XBASE + c) << 17;
            xmin = __uint_as_float(blo);
            xmax = __uint_as_float(blo + (1u << 17) - 1u);
        } else {                                     // y-side: key = 1.0f - x
            unsigned blo = (unsigned)(XBASE + (c - SIDE)) << 17;
            float ylo  = __uint_as_float(blo);
            float ymax = __uint_as_float(blo + (1u << 17) - 1u);
            float xa = 1.0f - ymax, xb = 1.0f - ylo; // x>=0.5: 8 ulps > rounding slack
            xmin = __uint_as_float(__float_as_uint(xa) - 8u);
            xmax = __uint_as_float(__float_as_uint(xb) + 8u);
        }
        int j = 0;                                   // deepest common ancestor
        while (j < 127) {
            float sp = l_split[j];
            if (xmax <= sp)      j = 2 * j + 1;      // whole bucket: x<=sp -> left
            else if (xmin > sp)  j = 2 * j + 2;      // whole bucket right
            else break;
        }
        ws_bucket[d * BSTR + c] = (unsigned char)j;
    }
}

__global__ __launch_bounds__(256) __attribute__((amdgpu_waves_per_eu(4, 4)))
void polya_eval(
    const float* __restrict__ x,            // (n,16)
    const float* __restrict__ ws_split,     // 16*128 f32
    const float* __restrict__ ws_value,     // 16*128 f32 (L1-resident gathers)
    const unsigned char* __restrict__ ws_bucket, // 16*BSTR u8
    float* __restrict__ out,
    int n)
{
    __shared__ float s_split[DIMS * 128];        // 8 KB
    __shared__ unsigned char s_buk[DIMS * BSTR]; // 25.6 KB   (33.8 KB total)
    for (int i = threadIdx.x; i < DIMS * 128; i += 256) s_split[i] = ws_split[i];
    {
        const unsigned* src = (const unsigned*)ws_bucket;
        unsigned* dst = (unsigned*)s_buk;
        for (int i = threadIdx.x; i < DIMS * BSTR / 4; i += 256) dst[i] = src[i];
    }
    __syncthreads();

    const int stride = gridDim.x * 256;
    for (int p = blockIdx.x * 256 + threadIdx.x; p < n; p += stride) {
        const float4* xr = reinterpret_cast<const float4*>(x + (size_t)p * DIMS);
        float4 a = xr[0], b4 = xr[1], c4 = xr[2], e4 = xr[3];
        float xs[DIMS] = {a.x, a.y, a.z, a.w,  b4.x, b4.y, b4.z, b4.w,
                          c4.x, c4.y, c4.z, c4.w,  e4.x, e4.y, e4.z, e4.w};
        int leaf[DIMS];
#pragma unroll
        for (int d = 0; d < DIMS; ++d) {
            const float xv = xs[d];
            const bool hiS = xv > 0.5f;
            const float key = hiS ? (1.0f - xv) : xv;
            int idx = (int)(__float_as_uint(key) >> 17) - XBASE + (hiS ? SIDE : 0);
            idx = min(max(idx, 0), NBUK - 1);            // defensive clamp
            int j = (int)s_buk[d * BSTR + idx];          // ancestor node
            while (j < 127) {                            // short exact descent
                const float sp = s_split[(d << 7) + j];
                j = 2 * j + 1 + (int)(xv > sp);          // x<=split -> left
            }
            leaf[d] = (d << 7) + (j - 127);
        }
        float vals[DIMS];
#pragma unroll
        for (int d = 0; d < DIMS; ++d)                   // 16 gathers in flight
            vals[d] = ws_value[leaf[d]];
        float acc = 0.0f;
#pragma unroll
        for (int d = 0; d < DIMS; ++d) acc += vals[d];
        out[p] = acc * 0.0625f;   // mean over 16 dims (exact /16)
    }
}

extern "C" void kernel_launch(void* const* d_in, const int* in_sizes, int n_in,
                              void* d_out, int out_size, void* d_ws, size_t ws_size,
                              hipStream_t stream) {
    const float* x       = (const float*)d_in[0];   // (n,16) f32
    const float* samples = (const float*)d_in[1];   // (16,255) f32
    float* out = (float*)d_out;
    const int n = in_sizes[0] / DIMS;

    float* ws_split = (float*)d_ws;                          // 8 KB
    float* ws_value = ws_split + DIMS * 128;                 // 8 KB
    unsigned char* ws_bucket = (unsigned char*)(ws_value + DIMS * 128); // 25.6 KB

    build_tables<<<DIMS, 256, 0, stream>>>(samples, ws_split, ws_value, ws_bucket);

    int blocks = (n + 255) / 256;
    if (blocks > 2048) blocks = 2048;
    polya_eval<<<blocks, 256, 0, stream>>>(x, ws_split, ws_value, ws_bucket, out, n);
}